// Round 3
// baseline (517.006 us; speedup 1.0000x reference)
//
#include <hip/hip_runtime.h>
#include <hip/hip_bf16.h>

#define N_NODES 4096
#define BATCH 16
#define IN_CH 128
#define HID 8
#define HEADS 4
#define F1 (HEADS*HID)   // 32
#define OUT_CH 64
#define MAXD 64          // padded degree; true max deg ~51 (two drifting 5x5 windows + self)

// ---------------- padded CSR build ----------------
__global__ void k_zero(int* counts, int* cursor) {
    int i = blockIdx.x * 256 + threadIdx.x;
    if (i < N_NODES) { counts[i] = 0; cursor[i] = 0; }
}

__global__ void k_count(const int* __restrict__ dstA, int E, int* counts) {
    int e = blockIdx.x * 256 + threadIdx.x;
    if (e < E) atomicAdd(&counts[dstA[e]], 1);
}

__global__ void k_initn(int* nbrp) {
    int i = blockIdx.x * 256 + threadIdx.x;
    if (i < N_NODES * MAXD) nbrp[i] = i >> 6;   // pad with self index (i / MAXD)
}

__global__ void k_fill(const int* __restrict__ srcA, const int* __restrict__ dstA, int E,
                       int* cursor, int* nbrp) {
    int e = blockIdx.x * 256 + threadIdx.x;
    if (e < E) {
        int n = dstA[e];
        int pos = atomicAdd(&cursor[n], 1);
        nbrp[n * MAXD + pos] = srcA[e];
    }
}

// ---------------- Layer 1 projection: feat1 = x_b @ W1, el1/er1 ----------------
__global__ __launch_bounds__(256) void k_feat1(const float* __restrict__ x,
                                               const float* __restrict__ W1,
                                               const float* __restrict__ al1,
                                               const float* __restrict__ ar1,
                                               float* __restrict__ feat1,
                                               float* __restrict__ el1,
                                               float* __restrict__ er1) {
    __shared__ float smem[256 * 33];     // phase 1: W1 (first 4096); phase 2: transpose tile
    __shared__ float lal[F1], lar[F1];
    int t = threadIdx.x;
    for (int i = t; i < IN_CH * F1; i += 256) smem[i] = W1[i];
    if (t < F1) { lal[t] = al1[t]; lar[t] = ar1[t]; }
    __syncthreads();

    int b = blockIdx.y;
    int n0 = blockIdx.x * 256;
    int n = n0 + t;
    const float* xp = x + (size_t)b * IN_CH * N_NODES + n;

    float acc[F1];
    #pragma unroll
    for (int k = 0; k < F1; k++) acc[k] = 0.f;
    #pragma unroll 4
    for (int c = 0; c < IN_CH; c++) {
        float xv = xp[(size_t)c * N_NODES];
        #pragma unroll
        for (int k = 0; k < F1; k++) acc[k] += xv * smem[c * F1 + k];
    }
    __syncthreads();   // everyone done with W1

    // el/er as coalesced float4 stores
    size_t row = (size_t)b * N_NODES + n;
    float4 e4l, e4r;
    float* pl = &e4l.x; float* pr = &e4r.x;
    #pragma unroll
    for (int h = 0; h < HEADS; h++) {
        float el = 0.f, er = 0.f;
        #pragma unroll
        for (int d = 0; d < HID; d++) {
            el += acc[h * HID + d] * lal[h * HID + d];
            er += acc[h * HID + d] * lar[h * HID + d];
        }
        pl[h] = el; pr[h] = er;
    }
    ((float4*)el1)[row] = e4l;
    ((float4*)er1)[row] = e4r;

    // transpose via LDS for coalesced feat1 stores
    #pragma unroll
    for (int k = 0; k < F1; k++) smem[t * 33 + k] = acc[k];
    __syncthreads();
    float* fp = feat1 + ((size_t)b * N_NODES + n0) * F1;
    #pragma unroll
    for (int i = 0; i < F1; i++) {
        int idx = i * 256 + t;
        fp[idx] = smem[(idx >> 5) * 33 + (idx & 31)];
    }
}

// ---------------- Layer 1 gather + softmax + bias + mish ----------------
// wave per (node, batch); lanes = (edge-slot pair: lane>>5, feature: lane&31)
__global__ __launch_bounds__(256) void k_gat1(const float* __restrict__ feat1,
                                              const float* __restrict__ el1,
                                              const float* __restrict__ er1,
                                              const int* __restrict__ nbrp,
                                              const int* __restrict__ deg,
                                              const float* __restrict__ b1v,
                                              float* __restrict__ h1) {
    int t = threadIdx.x;
    int lane = t & 63;
    int n = blockIdx.x * 4 + (t >> 6);
    int b = blockIdx.y;
    size_t brow = (size_t)b * N_NODES;
    int f = lane & 31;
    int h = f >> 3;
    int half = lane >> 5;
    int dg = deg[n];
    float ern = er1[(brow + n) * HEADS + h];
    const int* nb = nbrp + n * MAXD;

    float accv = 0.f, wsum = 0.f;
    for (int g = 0; g < MAXD / 8; g++) {
        if (g * 8 >= dg) break;              // wave-uniform
        #pragma unroll
        for (int u = 0; u < 4; u++) {
            int j = g * 8 + u * 2 + half;
            int s = nb[j];
            float e = el1[(brow + s) * HEADS + h] + ern;
            e = (e > 0.f) ? e : 0.2f * e;
            float w = (j < dg) ? __expf(e) : 0.f;
            wsum += w;
            accv += w * feat1[(brow + s) * F1 + f];
        }
    }
    accv += __shfl_xor(accv, 32, 64);
    wsum += __shfl_xor(wsum, 32, 64);

    float v = accv / wsum + b1v[f];
    float sp = log1pf(__expf(v));
    float out = v * tanhf(sp);
    if (half == 0) h1[(brow + n) * F1 + f] = out;
}

// ---------------- Layer 2 projection: feat2 = h1 @ W2, el2/er2 ----------------
__global__ __launch_bounds__(256) void k_feat2(const float* __restrict__ h1,
                                               const float* __restrict__ W2,
                                               const float* __restrict__ al2,
                                               const float* __restrict__ ar2,
                                               float* __restrict__ feat2,
                                               float* __restrict__ el2,
                                               float* __restrict__ er2) {
    __shared__ float lW2[F1 * OUT_CH];   // 8 KB
    int t = threadIdx.x;
    for (int i = t; i < F1 * OUT_CH; i += 256) lW2[i] = W2[i];
    __syncthreads();
    int lane = t & 63;
    int n = blockIdx.x * 4 + (t >> 6);
    int b = blockIdx.y;
    size_t row = (size_t)b * N_NODES + n;
    const float* hp = h1 + row * F1;
    float hval = (lane < F1) ? hp[lane] : 0.f;
    float acc = 0.f;
    #pragma unroll
    for (int k = 0; k < F1; k++) {
        float hv = __shfl(hval, k, 64);
        acc += hv * lW2[k * OUT_CH + lane];
    }
    feat2[row * OUT_CH + lane] = acc;
    float pl = acc * al2[lane];
    float pr = acc * ar2[lane];
    #pragma unroll
    for (int off = 32; off > 0; off >>= 1) {
        pl += __shfl_xor(pl, off, 64);
        pr += __shfl_xor(pr, off, 64);
    }
    if (lane == 0) { el2[row] = pl; er2[row] = pr; }
}

// ---------------- Layer 2 gather + softmax + bias ----------------
// wave per (node, batch); lane = out channel; fixed-trip groups of 4, uniform early-out
__global__ __launch_bounds__(256) void k_gat2(const float* __restrict__ feat2,
                                              const float* __restrict__ el2,
                                              const float* __restrict__ er2,
                                              const int* __restrict__ nbrp,
                                              const int* __restrict__ deg,
                                              const float* __restrict__ b2v,
                                              float* __restrict__ out2) {
    int t = threadIdx.x;
    int lane = t & 63;
    int n = blockIdx.x * 4 + (t >> 6);
    int b = blockIdx.y;
    size_t brow = (size_t)b * N_NODES;
    int dg = deg[n];
    float ern = er2[brow + n];
    const int* nb = nbrp + n * MAXD;

    float acc = 0.f, den = 0.f;
    for (int g = 0; g < MAXD / 4; g++) {
        if (g * 4 >= dg) break;              // wave-uniform
        #pragma unroll
        for (int u = 0; u < 4; u++) {
            int j = g * 4 + u;
            int s = nb[j];
            float e = el2[brow + s] + ern;
            e = (e > 0.f) ? e : 0.2f * e;
            float w = (j < dg) ? __expf(e) : 0.f;
            den += w;
            acc += w * feat2[(brow + s) * OUT_CH + lane];
        }
    }
    out2[(brow + n) * OUT_CH + lane] = acc / den + b2v[lane];
}

// ---------------- transpose (b, n, o) -> (b, o, n) ----------------
__global__ __launch_bounds__(256) void k_trans(const float* __restrict__ out2,
                                               float* __restrict__ out) {
    __shared__ float tile[64][65];
    int t = threadIdx.x;
    int lane = t & 63, w = t >> 6;
    int n0 = blockIdx.x * 64;
    int b = blockIdx.y;
    const float* src = out2 + ((size_t)b * N_NODES + n0) * OUT_CH;
    #pragma unroll
    for (int i = 0; i < 16; i++) {
        int r = i * 4 + w;
        tile[r][lane] = src[(size_t)r * OUT_CH + lane];
    }
    __syncthreads();
    float* dst = out + (size_t)b * OUT_CH * N_NODES + n0;
    #pragma unroll
    for (int i = 0; i < 16; i++) {
        int o = i * 4 + w;
        dst[(size_t)o * N_NODES + lane] = tile[lane][o];
    }
}

extern "C" void kernel_launch(void* const* d_in, const int* in_sizes, int n_in,
                              void* d_out, int out_size, void* d_ws, size_t ws_size,
                              hipStream_t stream) {
    const float* x   = (const float*)d_in[0];
    const float* W1  = (const float*)d_in[1];
    const float* al1 = (const float*)d_in[2];
    const float* ar1 = (const float*)d_in[3];
    const float* b1v = (const float*)d_in[4];
    const float* W2  = (const float*)d_in[5];
    const float* al2 = (const float*)d_in[6];
    const float* ar2 = (const float*)d_in[7];
    const float* b2v = (const float*)d_in[8];
    const int* srcA  = (const int*)d_in[9];
    const int* dstA  = (const int*)d_in[10];
    int E = in_sizes[9];

    char* ws = (char*)d_ws;
    int* counts = (int*)(ws);                     // 16 KB (= deg)
    int* cursor = (int*)(ws + 16384);             // 16 KB
    int* nbrp   = (int*)(ws + 32768);             // 1 MB (4096*64*4)
    float* feat1 = (float*)(ws + 1081344);                       // 8.39 MB
    float* el1   = (float*)(ws + 1081344 + 8388608);             // 1.05 MB
    float* er1   = (float*)(ws + 1081344 + 9437184);             // 1.05 MB
    float* h1    = (float*)(ws + 1081344 + 10485760);            // 8.39 MB
    float* feat2 = (float*)(ws + 1081344 + 18874368);            // 16.78 MB
    float* el2   = (float*)(ws + 1081344 + 35651584);            // 0.26 MB
    float* er2   = (float*)(ws + 1081344 + 35913728);            // 0.26 MB
    float* out2  = feat1;   // alias: feat1/el1/er1/h1 dead before k_gat2 writes

    float* out = (float*)d_out;
    dim3 blk(256);

    // padded CSR build
    k_zero <<<dim3((N_NODES + 255) / 256), blk, 0, stream>>>(counts, cursor);
    k_count<<<dim3((E + 255) / 256), blk, 0, stream>>>(dstA, E, counts);
    k_initn<<<dim3((N_NODES * MAXD + 255) / 256), blk, 0, stream>>>(nbrp);
    k_fill <<<dim3((E + 255) / 256), blk, 0, stream>>>(srcA, dstA, E, cursor, nbrp);

    // layer 1
    k_feat1<<<dim3(N_NODES / 256, BATCH), blk, 0, stream>>>(x, W1, al1, ar1, feat1, el1, er1);
    k_gat1 <<<dim3(N_NODES / 4, BATCH), blk, 0, stream>>>(feat1, el1, er1, nbrp, counts, b1v, h1);

    // layer 2
    k_feat2<<<dim3(N_NODES / 4, BATCH), blk, 0, stream>>>(h1, W2, al2, ar2, feat2, el2, er2);
    k_gat2 <<<dim3(N_NODES / 4, BATCH), blk, 0, stream>>>(feat2, el2, er2, nbrp, counts, b2v, out2);

    // output transpose
    k_trans<<<dim3(N_NODES / 64, BATCH), blk, 0, stream>>>(out2, out);
}

// Round 4
// 264.148 us; speedup vs baseline: 1.9573x; 1.9573x over previous
//
#include <hip/hip_runtime.h>
#include <hip/hip_bf16.h>

#define N_NODES 4096
#define BATCH 16
#define IN_CH 128
#define HID 8
#define HEADS 4
#define F1 (HEADS*HID)   // 32
#define OUT_CH 64
#define MAXD 64          // padded degree; true max ~51 (two drifting 5x5 windows + self)

// XCD-bijective swizzle for grid==4096: 8 XCDs x 512 contiguous nodes
__device__ __forceinline__ int node_swz(int bid) {
    return (bid & 7) * 512 + (bid >> 3);
}

// ---------------- graph build: init + fill (cursor ends up = degree) ----------------
__global__ void k_init(int* cursor, int* nbrp) {
    int i = blockIdx.x * 256 + threadIdx.x;
    if (i < N_NODES * MAXD) nbrp[i] = i >> 6;   // pad with self (i / MAXD)
    if (i < N_NODES) cursor[i] = 0;
}

__global__ void k_fill(const int* __restrict__ srcA, const int* __restrict__ dstA, int E,
                       int* cursor, int* nbrp) {
    int e = blockIdx.x * 256 + threadIdx.x;
    if (e < E) {
        int n = dstA[e];
        int pos = atomicAdd(&cursor[n], 1);
        nbrp[(n << 6) + pos] = srcA[e];
    }
}

// ---------------- Layer 1 projection -> feat1[n][b][32], el1/er1[n][b][4] ----------------
__global__ __launch_bounds__(256) void k_feat1(const float* __restrict__ x,
                                               const float* __restrict__ W1,
                                               const float* __restrict__ al1,
                                               const float* __restrict__ ar1,
                                               float* __restrict__ feat1,
                                               float* __restrict__ el1,
                                               float* __restrict__ er1) {
    __shared__ float smem[256 * 33];   // phase 1: W1 (4096 floats); phase 2: transpose tile
    __shared__ float lal[F1], lar[F1];
    int t = threadIdx.x;
    for (int i = t; i < IN_CH * F1; i += 256) smem[i] = W1[i];
    if (t < F1) { lal[t] = al1[t]; lar[t] = ar1[t]; }
    __syncthreads();

    int b = blockIdx.y;
    int n0 = blockIdx.x * 256;
    int n = n0 + t;
    const float* xp = x + (size_t)b * (IN_CH * N_NODES) + n;

    float acc[F1];
    #pragma unroll
    for (int k = 0; k < F1; k++) acc[k] = 0.f;
    #pragma unroll 4
    for (int c = 0; c < IN_CH; c++) {
        float xv = xp[(size_t)c * N_NODES];
        #pragma unroll
        for (int k = 0; k < F1; k++) acc[k] += xv * smem[c * F1 + k];
    }

    // el/er: [n][b][h] float4 store
    float4 e4l, e4r;
    float* pl = &e4l.x; float* pr = &e4r.x;
    #pragma unroll
    for (int h = 0; h < HEADS; h++) {
        float el = 0.f, er = 0.f;
        #pragma unroll
        for (int d = 0; d < HID; d++) {
            el += acc[h * HID + d] * lal[h * HID + d];
            er += acc[h * HID + d] * lar[h * HID + d];
        }
        pl[h] = el; pr[h] = er;
    }
    ((float4*)el1)[n * BATCH + b] = e4l;
    ((float4*)er1)[n * BATCH + b] = e4r;

    __syncthreads();   // all threads done reading W1
    #pragma unroll
    for (int k = 0; k < F1; k++) smem[t * 33 + k] = acc[k];
    __syncthreads();
    // coalesced store: feat1[(n0+nn)*512 + b*32 + f]
    float* fp = feat1 + (size_t)n0 * (BATCH * F1) + b * F1;
    #pragma unroll
    for (int k = 0; k < F1; k++) {
        int idx = k * 256 + t;
        int nn = idx >> 5, f = idx & 31;
        fp[nn * (BATCH * F1) + f] = smem[nn * 33 + f];
    }
}

// ---------------- Layer 1 gather: block per node, all batches ----------------
__global__ __launch_bounds__(256) void k_gat1(const float* __restrict__ feat1,
                                              const float* __restrict__ el1,
                                              const float* __restrict__ er1,
                                              const int* __restrict__ nbrp,
                                              const int* __restrict__ deg,
                                              const float* __restrict__ b1v,
                                              float* __restrict__ h1) {
    int t = threadIdx.x;
    int n = node_swz(blockIdx.x);
    int f2 = t & 15;                 // float2 slot over 32 feats
    int eoff = ((t >> 4) << 2) + (f2 >> 2);   // b*4 + h
    int dg = deg[n];
    const int* nb = nbrp + (n << 6);
    float ern = er1[(n << 6) + eoff];
    int t2 = t << 1;

    float ax = 0.f, ay = 0.f, wsum = 0.f;
    for (int g = 0; g < MAXD / 4; g++) {
        if (g * 4 >= dg) break;      // block-uniform
        #pragma unroll
        for (int u = 0; u < 4; u++) {
            int j = g * 4 + u;
            int s = nb[j];
            float e = el1[(s << 6) + eoff] + ern;
            e = (e > 0.f) ? e : 0.2f * e;
            float w = (j < dg) ? __expf(e) : 0.f;
            wsum += w;
            float2 f = *(const float2*)&feat1[(s << 9) + t2];
            ax += w * f.x; ay += w * f.y;
        }
    }
    float inv = 1.f / wsum;
    float2 bb = *(const float2*)&b1v[f2 * 2];
    float v0 = ax * inv + bb.x;
    float v1 = ay * inv + bb.y;
    // mish(v) = v * t(t+2)/(t(t+2)+2), t = e^v
    float e0 = __expf(v0), e1 = __expf(v1);
    float p0 = e0 * (e0 + 2.f), p1 = e1 * (e1 + 2.f);
    float2 o = { v0 * p0 / (p0 + 2.f), v1 * p1 / (p1 + 2.f) };
    *(float2*)&h1[(n << 9) + t2] = o;
}

// ---------------- Layer 2 projection: block per node ----------------
__global__ __launch_bounds__(256) void k_feat2(const float* __restrict__ h1,
                                               const float* __restrict__ W2,
                                               const float* __restrict__ al2,
                                               const float* __restrict__ ar2,
                                               float* __restrict__ feat2,
                                               float* __restrict__ el2,
                                               float* __restrict__ er2) {
    __shared__ float lW2[F1 * OUT_CH];   // 8 KB
    __shared__ float lh[BATCH * F1];     // 2 KB
    __shared__ float lae[2 * OUT_CH];
    int t = threadIdx.x;
    int n = node_swz(blockIdx.x);
    for (int i = t; i < F1 * OUT_CH; i += 256) lW2[i] = W2[i];
    if (t < OUT_CH) { lae[t] = al2[t]; lae[OUT_CH + t] = ar2[t]; }
    *(float2*)&lh[t * 2] = *(const float2*)&h1[(n << 9) + t * 2];
    __syncthreads();

    int b = t >> 4, c4 = t & 15;
    float hreg[F1];
    #pragma unroll
    for (int k = 0; k < F1; k++) hreg[k] = lh[b * F1 + k];
    float4 acc = {0.f, 0.f, 0.f, 0.f};
    #pragma unroll
    for (int k = 0; k < F1; k++) {
        float4 w = *(float4*)&lW2[k * OUT_CH + c4 * 4];
        acc.x += hreg[k] * w.x; acc.y += hreg[k] * w.y;
        acc.z += hreg[k] * w.z; acc.w += hreg[k] * w.w;
    }
    *(float4*)&feat2[(n << 10) + (t << 2)] = acc;

    float4 a4 = *(float4*)&lae[c4 * 4];
    float4 r4 = *(float4*)&lae[OUT_CH + c4 * 4];
    float pl = acc.x * a4.x + acc.y * a4.y + acc.z * a4.z + acc.w * a4.w;
    float pr = acc.x * r4.x + acc.y * r4.y + acc.z * r4.z + acc.w * r4.w;
    #pragma unroll
    for (int off = 1; off < 16; off <<= 1) {
        pl += __shfl_xor(pl, off, 64);
        pr += __shfl_xor(pr, off, 64);
    }
    if (c4 == 0) { el2[n * BATCH + b] = pl; er2[n * BATCH + b] = pr; }
}

// ---------------- Layer 2 gather: block per node ----------------
__global__ __launch_bounds__(256) void k_gat2(const float* __restrict__ feat2,
                                              const float* __restrict__ el2,
                                              const float* __restrict__ er2,
                                              const int* __restrict__ nbrp,
                                              const int* __restrict__ deg,
                                              const float* __restrict__ b2v,
                                              float* __restrict__ out2) {
    int t = threadIdx.x;
    int n = node_swz(blockIdx.x);
    int b = t >> 4, c4 = t & 15;
    int dg = deg[n];
    const int* nb = nbrp + (n << 6);
    float ern = er2[n * BATCH + b];
    int t4 = t << 2;

    float4 acc = {0.f, 0.f, 0.f, 0.f};
    float den = 0.f;
    for (int g = 0; g < MAXD / 4; g++) {
        if (g * 4 >= dg) break;      // block-uniform
        #pragma unroll
        for (int u = 0; u < 4; u++) {
            int j = g * 4 + u;
            int s = nb[j];
            float e = el2[(s << 4) + b] + ern;
            e = (e > 0.f) ? e : 0.2f * e;
            float w = (j < dg) ? __expf(e) : 0.f;
            den += w;
            float4 f = *(const float4*)&feat2[(s << 10) + t4];
            acc.x += w * f.x; acc.y += w * f.y; acc.z += w * f.z; acc.w += w * f.w;
        }
    }
    float inv = 1.f / den;
    float4 bb = *(const float4*)&b2v[c4 * 4];
    float4 o = { acc.x * inv + bb.x, acc.y * inv + bb.y,
                 acc.z * inv + bb.z, acc.w * inv + bb.w };
    *(float4*)&out2[(n << 10) + t4] = o;
}

// ---------------- transpose out2[n][b][c] -> out[b][c][n] ----------------
__global__ __launch_bounds__(256) void k_trans(const float* __restrict__ out2,
                                               float* __restrict__ out) {
    __shared__ float tile[64][65];
    int t = threadIdx.x;
    int b = blockIdx.y;
    int n0 = blockIdx.x * 64;
    int i = t >> 2;
    int c0 = (t & 3) * 4;
    #pragma unroll
    for (int p = 0; p < 4; p++) {
        int c = c0 + p * 16;
        float4 v = *(const float4*)&out2[(size_t)(n0 + i) * (BATCH * OUT_CH) + b * OUT_CH + c];
        tile[i][c] = v.x; tile[i][c + 1] = v.y; tile[i][c + 2] = v.z; tile[i][c + 3] = v.w;
    }
    __syncthreads();
    int nl = t & 63;
    int cw = t >> 6;
    #pragma unroll
    for (int q = 0; q < 16; q++) {
        int c = q * 4 + cw;
        out[(size_t)(b * OUT_CH + c) * N_NODES + n0 + nl] = tile[nl][c];
    }
}

extern "C" void kernel_launch(void* const* d_in, const int* in_sizes, int n_in,
                              void* d_out, int out_size, void* d_ws, size_t ws_size,
                              hipStream_t stream) {
    const float* x   = (const float*)d_in[0];
    const float* W1  = (const float*)d_in[1];
    const float* al1 = (const float*)d_in[2];
    const float* ar1 = (const float*)d_in[3];
    const float* b1v = (const float*)d_in[4];
    const float* W2  = (const float*)d_in[5];
    const float* al2 = (const float*)d_in[6];
    const float* ar2 = (const float*)d_in[7];
    const float* b2v = (const float*)d_in[8];
    const int* srcA  = (const int*)d_in[9];
    const int* dstA  = (const int*)d_in[10];
    int E = in_sizes[9];

    char* ws = (char*)d_ws;
    int*   cursor = (int*)(ws);                    // 16 KB; after k_fill == degree
    int*   nbrp   = (int*)(ws + 16384);            // 1 MB
    float* feat1  = (float*)(ws + 1064960);        // 8.39 MB  [n][b][32]
    float* el1    = (float*)(ws + 9453568);        // 1.05 MB  [n][b][4]
    float* er1    = (float*)(ws + 10502144);       // 1.05 MB
    float* h1     = (float*)(ws + 11550720);       // 8.39 MB  [n][b][32]
    float* feat2  = (float*)(ws + 19939328);       // 16.78 MB [n][b][64]
    float* el2    = (float*)(ws + 36716544);       // 0.26 MB  [n][b]
    float* er2    = (float*)(ws + 36978688);       // 0.26 MB
    float* out2   = feat1;  // 16.78 MB alias over feat1/el1/er1/h1 (all dead by k_gat2)

    float* out = (float*)d_out;
    dim3 blk(256);

    k_init<<<dim3((N_NODES * MAXD + 255) / 256), blk, 0, stream>>>(cursor, nbrp);
    k_fill<<<dim3((E + 255) / 256), blk, 0, stream>>>(srcA, dstA, E, cursor, nbrp);

    k_feat1<<<dim3(N_NODES / 256, BATCH), blk, 0, stream>>>(x, W1, al1, ar1, feat1, el1, er1);
    k_gat1 <<<dim3(N_NODES), blk, 0, stream>>>(feat1, el1, er1, nbrp, cursor, b1v, h1);

    k_feat2<<<dim3(N_NODES), blk, 0, stream>>>(h1, W2, al2, ar2, feat2, el2, er2);
    k_gat2 <<<dim3(N_NODES), blk, 0, stream>>>(feat2, el2, er2, nbrp, cursor, b2v, out2);

    k_trans<<<dim3(N_NODES / 64, BATCH), blk, 0, stream>>>(out2, out);
}

// Round 6
// 218.783 us; speedup vs baseline: 2.3631x; 1.2074x over previous
//
#include <hip/hip_runtime.h>
#include <hip/hip_bf16.h>

#define N_NODES 4096
#define BATCH 16
#define IN_CH 128
#define HID 8
#define HEADS 4
#define F1 (HEADS*HID)   // 32
#define OUT_CH 64
#define MAXD 64          // padded degree; true max ~51 (two drifting 5x5 windows + self)

// XCD-bijective swizzle for grid==4096: 8 XCDs x 512 contiguous nodes
__device__ __forceinline__ int node_swz(int bid) {
    return (bid & 7) * 512 + (bid >> 3);
}

// ---------------- graph build: init + fill (cursor ends up = degree) ----------------
__global__ void k_init(int* cursor, int* nbrp) {
    int i = blockIdx.x * 256 + threadIdx.x;
    if (i < N_NODES * MAXD) nbrp[i] = i >> 6;   // pad with self (i / MAXD)
    if (i < N_NODES) cursor[i] = 0;
}

__global__ void k_fill(const int* __restrict__ srcA, const int* __restrict__ dstA, int E,
                       int* cursor, int* nbrp) {
    int e = blockIdx.x * 256 + threadIdx.x;
    if (e < E) {
        int n = dstA[e];
        int pos = atomicAdd(&cursor[n], 1);
        nbrp[(n << 6) + pos] = srcA[e];
    }
}

// ---------------- Layer 1 projection -> feat1[n][b][32], el1/er1[n][b][4] ----------------
// 64 nodes x 1 batch per block; thread t = q*64 + nl; head q owns outputs q*8..q*8+8.
// Grid (64, 16) = 1024 blocks -> ~4 blocks/CU (round-4 fix: was 256 blocks = 1/CU, 8% occ).
__global__ __launch_bounds__(256) void k_feat1(const float* __restrict__ x,
                                               const float* __restrict__ W1,
                                               const float* __restrict__ al1,
                                               const float* __restrict__ ar1,
                                               float* __restrict__ feat1,
                                               float* __restrict__ el1,
                                               float* __restrict__ er1) {
    __shared__ float lW1[IN_CH * F1];    // 16 KB
    __shared__ float lal[F1], lar[F1];
    __shared__ float lt[64 * 33];        // 8.25 KB transpose tile
    __shared__ float lel[64 * 4], ler[64 * 4];   // 2 KB
    int t = threadIdx.x;
    for (int i = t; i < IN_CH * F1; i += 256) lW1[i] = W1[i];
    if (t < F1) { lal[t] = al1[t]; lar[t] = ar1[t]; }
    __syncthreads();

    int b = blockIdx.y;
    int n0 = blockIdx.x * 64;
    int q = t >> 6;          // channel group == head == wave id
    int nl = t & 63;
    int n = n0 + nl;
    const float* xp = x + (size_t)b * (IN_CH * N_NODES) + n;
    const float* wq = lW1 + q * HID;

    float acc[HID];
    #pragma unroll
    for (int i = 0; i < HID; i++) acc[i] = 0.f;
    #pragma unroll 4
    for (int c = 0; c < IN_CH; c++) {
        float xv = xp[(size_t)c * N_NODES];          // 64-lane coalesced
        #pragma unroll
        for (int i = 0; i < HID; i++) acc[i] += xv * wq[c * F1 + i];   // LDS broadcast
    }

    // head-q attention dots (no cross-thread reduce needed: HID==8==slice width)
    float el = 0.f, er = 0.f;
    #pragma unroll
    for (int i = 0; i < HID; i++) {
        el += acc[i] * lal[q * HID + i];
        er += acc[i] * lar[q * HID + i];
    }
    lel[nl * 4 + q] = el;
    ler[nl * 4 + q] = er;

    // transpose tile for coalesced feat1 stores
    #pragma unroll
    for (int i = 0; i < HID; i++) lt[nl * 33 + q * HID + i] = acc[i];
    __syncthreads();

    float* fp = feat1 + (size_t)n0 * (BATCH * F1) + b * F1;
    #pragma unroll
    for (int k = 0; k < 8; k++) {
        int idx = k * 256 + t;          // 64 nodes * 32 feats
        int nn = idx >> 5, f = idx & 31;
        fp[nn * (BATCH * F1) + f] = lt[nn * 33 + f];
    }
    if (t < 64) {
        ((float4*)el1)[(n0 + t) * BATCH + b] = *(float4*)&lel[t * 4];
        ((float4*)er1)[(n0 + t) * BATCH + b] = *(float4*)&ler[t * 4];
    }
}

// ---------------- Layer 1 gather: block per node, all batches ----------------
__global__ __launch_bounds__(256) void k_gat1(const float* __restrict__ feat1,
                                              const float* __restrict__ el1,
                                              const float* __restrict__ er1,
                                              const int* __restrict__ nbrp,
                                              const int* __restrict__ deg,
                                              const float* __restrict__ b1v,
                                              float* __restrict__ h1) {
    int t = threadIdx.x;
    int n = node_swz(blockIdx.x);
    int f2 = t & 15;                 // float2 slot over 32 feats
    int eoff = ((t >> 4) << 2) + (f2 >> 2);   // b*4 + h
    int dg = deg[n];
    const int* nb = nbrp + (n << 6);
    float ern = er1[(n << 6) + eoff];
    int t2 = t << 1;

    float ax = 0.f, ay = 0.f, wsum = 0.f;
    for (int g = 0; g < MAXD / 4; g++) {
        if (g * 4 >= dg) break;      // block-uniform
        #pragma unroll
        for (int u = 0; u < 4; u++) {
            int j = g * 4 + u;
            int s = nb[j];
            float e = el1[(s << 6) + eoff] + ern;
            e = (e > 0.f) ? e : 0.2f * e;
            float w = (j < dg) ? __expf(e) : 0.f;
            wsum += w;
            float2 f = *(const float2*)&feat1[(s << 9) + t2];
            ax += w * f.x; ay += w * f.y;
        }
    }
    float inv = 1.f / wsum;
    float2 bb = *(const float2*)&b1v[f2 * 2];
    float v0 = ax * inv + bb.x;
    float v1 = ay * inv + bb.y;
    // mish(v) = v * t(t+2)/(t(t+2)+2), t = e^v
    float e0 = __expf(v0), e1 = __expf(v1);
    float p0 = e0 * (e0 + 2.f), p1 = e1 * (e1 + 2.f);
    float2 o = { v0 * p0 / (p0 + 2.f), v1 * p1 / (p1 + 2.f) };
    *(float2*)&h1[(n << 9) + t2] = o;
}

// ---------------- Layer 2 projection: block per node ----------------
__global__ __launch_bounds__(256) void k_feat2(const float* __restrict__ h1,
                                               const float* __restrict__ W2,
                                               const float* __restrict__ al2,
                                               const float* __restrict__ ar2,
                                               float* __restrict__ feat2,
                                               float* __restrict__ el2,
                                               float* __restrict__ er2) {
    __shared__ float lW2[F1 * OUT_CH];   // 8 KB
    __shared__ float lh[BATCH * F1];     // 2 KB
    __shared__ float lae[2 * OUT_CH];
    int t = threadIdx.x;
    int n = node_swz(blockIdx.x);
    for (int i = t; i < F1 * OUT_CH; i += 256) lW2[i] = W2[i];
    if (t < OUT_CH) { lae[t] = al2[t]; lae[OUT_CH + t] = ar2[t]; }
    *(float2*)&lh[t * 2] = *(const float2*)&h1[(n << 9) + t * 2];
    __syncthreads();

    int b = t >> 4, c4 = t & 15;
    float hreg[F1];
    #pragma unroll
    for (int k = 0; k < F1; k++) hreg[k] = lh[b * F1 + k];
    float4 acc = {0.f, 0.f, 0.f, 0.f};
    #pragma unroll
    for (int k = 0; k < F1; k++) {
        float4 w = *(float4*)&lW2[k * OUT_CH + c4 * 4];
        acc.x += hreg[k] * w.x; acc.y += hreg[k] * w.y;
        acc.z += hreg[k] * w.z; acc.w += hreg[k] * w.w;
    }
    *(float4*)&feat2[(n << 10) + (t << 2)] = acc;

    float4 a4 = *(float4*)&lae[c4 * 4];
    float4 r4 = *(float4*)&lae[OUT_CH + c4 * 4];
    float pl = acc.x * a4.x + acc.y * a4.y + acc.z * a4.z + acc.w * a4.w;
    float pr = acc.x * r4.x + acc.y * r4.y + acc.z * r4.z + acc.w * r4.w;
    #pragma unroll
    for (int off = 1; off < 16; off <<= 1) {
        pl += __shfl_xor(pl, off, 64);
        pr += __shfl_xor(pr, off, 64);
    }
    if (c4 == 0) { el2[n * BATCH + b] = pl; er2[n * BATCH + b] = pr; }
}

// ---------------- Layer 2 gather: block per node ----------------
__global__ __launch_bounds__(256) void k_gat2(const float* __restrict__ feat2,
                                              const float* __restrict__ el2,
                                              const float* __restrict__ er2,
                                              const int* __restrict__ nbrp,
                                              const int* __restrict__ deg,
                                              const float* __restrict__ b2v,
                                              float* __restrict__ out2) {
    int t = threadIdx.x;
    int n = node_swz(blockIdx.x);
    int b = t >> 4, c4 = t & 15;
    int dg = deg[n];
    const int* nb = nbrp + (n << 6);
    float ern = er2[n * BATCH + b];
    int t4 = t << 2;

    float4 acc = {0.f, 0.f, 0.f, 0.f};
    float den = 0.f;
    for (int g = 0; g < MAXD / 4; g++) {
        if (g * 4 >= dg) break;      // block-uniform
        #pragma unroll
        for (int u = 0; u < 4; u++) {
            int j = g * 4 + u;
            int s = nb[j];
            float e = el2[(s << 4) + b] + ern;
            e = (e > 0.f) ? e : 0.2f * e;
            float w = (j < dg) ? __expf(e) : 0.f;
            den += w;
            float4 f = *(const float4*)&feat2[(s << 10) + t4];
            acc.x += w * f.x; acc.y += w * f.y; acc.z += w * f.z; acc.w += w * f.w;
        }
    }
    float inv = 1.f / den;
    float4 bb = *(const float4*)&b2v[c4 * 4];
    float4 o = { acc.x * inv + bb.x, acc.y * inv + bb.y,
                 acc.z * inv + bb.z, acc.w * inv + bb.w };
    *(float4*)&out2[(n << 10) + t4] = o;
}

// ---------------- transpose out2[n][b][c] -> out[b][c][n] ----------------
__global__ __launch_bounds__(256) void k_trans(const float* __restrict__ out2,
                                               float* __restrict__ out) {
    __shared__ float tile[64][65];
    int t = threadIdx.x;
    int b = blockIdx.y;
    int n0 = blockIdx.x * 64;
    int i = t >> 2;
    int c0 = (t & 3) * 4;
    #pragma unroll
    for (int p = 0; p < 4; p++) {
        int c = c0 + p * 16;
        float4 v = *(const float4*)&out2[(size_t)(n0 + i) * (BATCH * OUT_CH) + b * OUT_CH + c];
        tile[i][c] = v.x; tile[i][c + 1] = v.y; tile[i][c + 2] = v.z; tile[i][c + 3] = v.w;
    }
    __syncthreads();
    int nl = t & 63;
    int cw = t >> 6;
    #pragma unroll
    for (int q = 0; q < 16; q++) {
        int c = q * 4 + cw;
        out[(size_t)(b * OUT_CH + c) * N_NODES + n0 + nl] = tile[nl][c];
    }
}

extern "C" void kernel_launch(void* const* d_in, const int* in_sizes, int n_in,
                              void* d_out, int out_size, void* d_ws, size_t ws_size,
                              hipStream_t stream) {
    const float* x   = (const float*)d_in[0];
    const float* W1  = (const float*)d_in[1];
    const float* al1 = (const float*)d_in[2];
    const float* ar1 = (const float*)d_in[3];
    const float* b1v = (const float*)d_in[4];
    const float* W2  = (const float*)d_in[5];
    const float* al2 = (const float*)d_in[6];
    const float* ar2 = (const float*)d_in[7];
    const float* b2v = (const float*)d_in[8];
    const int* srcA  = (const int*)d_in[9];
    const int* dstA  = (const int*)d_in[10];
    int E = in_sizes[9];

    char* ws = (char*)d_ws;
    int*   cursor = (int*)(ws);                    // 16 KB; after k_fill == degree
    int*   nbrp   = (int*)(ws + 16384);            // 1 MB
    float* feat1  = (float*)(ws + 1064960);        // 8.39 MB  [n][b][32]
    float* el1    = (float*)(ws + 9453568);        // 1.05 MB  [n][b][4]
    float* er1    = (float*)(ws + 10502144);       // 1.05 MB
    float* h1     = (float*)(ws + 11550720);       // 8.39 MB  [n][b][32]
    float* feat2  = (float*)(ws + 19939328);       // 16.78 MB [n][b][64]
    float* el2    = (float*)(ws + 36716544);       // 0.26 MB  [n][b]
    float* er2    = (float*)(ws + 36978688);       // 0.26 MB
    float* out2   = feat1;  // 16.78 MB alias over feat1/el1/er1/h1 (all dead by k_gat2)

    float* out = (float*)d_out;
    dim3 blk(256);

    k_init<<<dim3((N_NODES * MAXD + 255) / 256), blk, 0, stream>>>(cursor, nbrp);
    k_fill<<<dim3((E + 255) / 256), blk, 0, stream>>>(srcA, dstA, E, cursor, nbrp);

    k_feat1<<<dim3(N_NODES / 64, BATCH), blk, 0, stream>>>(x, W1, al1, ar1, feat1, el1, er1);
    k_gat1 <<<dim3(N_NODES), blk, 0, stream>>>(feat1, el1, er1, nbrp, cursor, b1v, h1);

    k_feat2<<<dim3(N_NODES), blk, 0, stream>>>(h1, W2, al2, ar2, feat2, el2, er2);
    k_gat2 <<<dim3(N_NODES), blk, 0, stream>>>(feat2, el2, er2, nbrp, cursor, b2v, out2);

    k_trans<<<dim3(N_NODES / 64, BATCH), blk, 0, stream>>>(out2, out);
}

// Round 7
// 211.380 us; speedup vs baseline: 2.4459x; 1.0350x over previous
//
#include <hip/hip_runtime.h>
#include <hip/hip_bf16.h>

#define N_NODES 4096
#define BATCH 16
#define IN_CH 128
#define HID 8
#define HEADS 4
#define F1 (HEADS*HID)   // 32
#define OUT_CH 64
#define MAXD 64          // padded degree; true max ~51 (two drifting 5x5 windows + self)

// XCD-bijective swizzle for grid==4096: 8 XCDs x 512 contiguous nodes
__device__ __forceinline__ int node_swz(int bid) {
    return (bid & 7) * 512 + (bid >> 3);
}

// ---------------- graph build: init + fill (cursor ends up = degree) ----------------
__global__ void k_init(int* cursor, int* nbrp) {
    int i = blockIdx.x * 256 + threadIdx.x;
    if (i < N_NODES * MAXD) nbrp[i] = i >> 6;   // pad with self (i / MAXD)
    if (i < N_NODES) cursor[i] = 0;
}

__global__ void k_fill(const int* __restrict__ srcA, const int* __restrict__ dstA, int E,
                       int* cursor, int* nbrp) {
    int e = blockIdx.x * 256 + threadIdx.x;
    if (e < E) {
        int n = dstA[e];
        int pos = atomicAdd(&cursor[n], 1);
        nbrp[(n << 6) + pos] = srcA[e];
    }
}

// ---------------- Layer 1 projection -> feat1[n][b][32], el1/er1[n][b][4] ----------------
// 64 nodes x 1 batch per block; thread t = q*64 + nl; head q owns outputs q*8..q*8+8.
__global__ __launch_bounds__(256) void k_feat1(const float* __restrict__ x,
                                               const float* __restrict__ W1,
                                               const float* __restrict__ al1,
                                               const float* __restrict__ ar1,
                                               float* __restrict__ feat1,
                                               float* __restrict__ el1,
                                               float* __restrict__ er1) {
    __shared__ float lW1[IN_CH * F1];    // 16 KB
    __shared__ float lal[F1], lar[F1];
    __shared__ float lt[64 * 33];        // 8.25 KB transpose tile
    __shared__ float lel[64 * 4], ler[64 * 4];   // 2 KB
    int t = threadIdx.x;
    for (int i = t; i < IN_CH * F1; i += 256) lW1[i] = W1[i];
    if (t < F1) { lal[t] = al1[t]; lar[t] = ar1[t]; }
    __syncthreads();

    int b = blockIdx.y;
    int n0 = blockIdx.x * 64;
    int q = t >> 6;          // channel group == head == wave id
    int nl = t & 63;
    int n = n0 + nl;
    const float* xp = x + (size_t)b * (IN_CH * N_NODES) + n;
    const float* wq = lW1 + q * HID;

    float acc[HID];
    #pragma unroll
    for (int i = 0; i < HID; i++) acc[i] = 0.f;
    #pragma unroll 4
    for (int c = 0; c < IN_CH; c++) {
        float xv = xp[(size_t)c * N_NODES];          // 64-lane coalesced
        #pragma unroll
        for (int i = 0; i < HID; i++) acc[i] += xv * wq[c * F1 + i];   // LDS broadcast
    }

    float el = 0.f, er = 0.f;
    #pragma unroll
    for (int i = 0; i < HID; i++) {
        el += acc[i] * lal[q * HID + i];
        er += acc[i] * lar[q * HID + i];
    }
    lel[nl * 4 + q] = el;
    ler[nl * 4 + q] = er;

    #pragma unroll
    for (int i = 0; i < HID; i++) lt[nl * 33 + q * HID + i] = acc[i];
    __syncthreads();

    float* fp = feat1 + (size_t)n0 * (BATCH * F1) + b * F1;
    #pragma unroll
    for (int k = 0; k < 8; k++) {
        int idx = k * 256 + t;          // 64 nodes * 32 feats
        int nn = idx >> 5, f = idx & 31;
        fp[nn * (BATCH * F1) + f] = lt[nn * 33 + f];
    }
    if (t < 64) {
        ((float4*)el1)[(n0 + t) * BATCH + b] = *(float4*)&lel[t * 4];
        ((float4*)er1)[(n0 + t) * BATCH + b] = *(float4*)&ler[t * 4];
    }
}

// ---------------- Fused layer-1 gather + mish + layer-2 projection ----------------
// Block per node. Phase A: per-edge weights w[j][b][h] computed ONCE into LDS
// (was 16x redundant per-thread exp). Phase B: gather with ds_read broadcast of w.
// Phase C: h (in LDS) @ W2 -> feat2, el2, er2. h1 never touches global memory.
__global__ __launch_bounds__(256) void k_gat1f(const float* __restrict__ feat1,
                                               const float* __restrict__ el1,
                                               const float* __restrict__ er1,
                                               const int* __restrict__ nbrp,
                                               const int* __restrict__ deg,
                                               const float* __restrict__ b1v,
                                               const float* __restrict__ W2,
                                               const float* __restrict__ al2,
                                               const float* __restrict__ ar2,
                                               float* __restrict__ feat2,
                                               float* __restrict__ el2,
                                               float* __restrict__ er2) {
    __shared__ float lw[MAXD * 64];      // 16 KB: w[j][b*4+h]
    __shared__ float lW2[F1 * OUT_CH];   // 8 KB
    __shared__ float lh[BATCH * F1];     // 2 KB
    __shared__ float lae[2 * OUT_CH];    // 512 B
    __shared__ float lb1[F1];
    int t = threadIdx.x;
    int n = node_swz(blockIdx.x);
    for (int i = t; i < F1 * OUT_CH; i += 256) lW2[i] = W2[i];
    if (t < 2 * OUT_CH) lae[t] = (t < OUT_CH) ? al2[t] : ar2[t - OUT_CH];
    if (t < F1) lb1[t] = b1v[t];

    int dg = deg[n];
    const int* nb = nbrp + (n << 6);

    // phase A: 4096 weights, 16/thread; idx = j*64 + b*4 + h
    float ern = er1[(n << 6) + (t & 63)];      // (t&63) == idx&63 for every r
    #pragma unroll
    for (int r = 0; r < 16; r++) {
        int idx = r * 256 + t;
        int j = idx >> 6;                      // wave-uniform
        int s = nb[j];
        float e = el1[(s << 6) + (idx & 63)] + ern;   // coalesced 256B per wave
        e = (e > 0.f) ? e : 0.2f * e;
        lw[idx] = (j < dg) ? __expf(e) : 0.f;
    }
    __syncthreads();

    // phase B: gather; thread = (b = t>>4, c2 = t&15 float2 slot), h = c2>>2
    int b = t >> 4, c2 = t & 15;
    int woff = (b << 2) + (c2 >> 2);
    int t2 = t << 1;
    float ax = 0.f, ay = 0.f, wsum = 0.f;
    for (int g = 0; g < MAXD / 8; g++) {
        if (g * 8 >= dg) break;                // block-uniform
        #pragma unroll
        for (int u = 0; u < 8; u++) {
            int j = g * 8 + u;
            int s = nb[j];                     // scalar load
            float w = lw[(j << 6) + woff];     // conflict-free broadcast
            wsum += w;
            float2 f = *(const float2*)&feat1[(s << 9) + t2];
            ax += w * f.x; ay += w * f.y;
        }
    }
    float inv = 1.f / wsum;
    float v0 = ax * inv + lb1[c2 * 2];
    float v1 = ay * inv + lb1[c2 * 2 + 1];
    // mish(v) = v * p/(p+2), p = t(t+2), t = e^v
    float e0 = __expf(v0), e1 = __expf(v1);
    float p0 = e0 * (e0 + 2.f), p1 = e1 * (e1 + 2.f);
    lh[b * F1 + c2 * 2]     = v0 * p0 / (p0 + 2.f);
    lh[b * F1 + c2 * 2 + 1] = v1 * p1 / (p1 + 2.f);
    __syncthreads();

    // phase C: project 32 -> 64; thread = (b, c4 = t&15)
    int c4 = t & 15;
    float hreg[F1];
    #pragma unroll
    for (int k = 0; k < F1; k++) hreg[k] = lh[b * F1 + k];
    float4 acc = {0.f, 0.f, 0.f, 0.f};
    #pragma unroll
    for (int k = 0; k < F1; k++) {
        float4 w4 = *(float4*)&lW2[k * OUT_CH + c4 * 4];
        acc.x += hreg[k] * w4.x; acc.y += hreg[k] * w4.y;
        acc.z += hreg[k] * w4.z; acc.w += hreg[k] * w4.w;
    }
    *(float4*)&feat2[(n << 10) + (t << 2)] = acc;

    float4 a4 = *(float4*)&lae[c4 * 4];
    float4 r4 = *(float4*)&lae[OUT_CH + c4 * 4];
    float pl = acc.x * a4.x + acc.y * a4.y + acc.z * a4.z + acc.w * a4.w;
    float pr = acc.x * r4.x + acc.y * r4.y + acc.z * r4.z + acc.w * r4.w;
    #pragma unroll
    for (int off = 1; off < 16; off <<= 1) {
        pl += __shfl_xor(pl, off, 64);
        pr += __shfl_xor(pr, off, 64);
    }
    if (c4 == 0) { el2[(n << 4) + b] = pl; er2[(n << 4) + b] = pr; }
}

// ---------------- Layer 2 gather: LDS weight table + broadcast ds_read ----------------
__global__ __launch_bounds__(256) void k_gat2(const float* __restrict__ feat2,
                                              const float* __restrict__ el2,
                                              const float* __restrict__ er2,
                                              const int* __restrict__ nbrp,
                                              const int* __restrict__ deg,
                                              const float* __restrict__ b2v,
                                              float* __restrict__ out2) {
    __shared__ float lw2[MAXD * BATCH];  // 4 KB: w[j][b]
    int t = threadIdx.x;
    int n = node_swz(blockIdx.x);
    int dg = deg[n];
    const int* nb = nbrp + (n << 6);

    // phase A: 1024 weights, 4/thread; idx = j*16 + b
    float ern = er2[(n << 4) + (t & 15)];
    #pragma unroll
    for (int r = 0; r < 4; r++) {
        int idx = r * 256 + t;
        int j = idx >> 4;
        int s = nb[j];
        float e = el2[(s << 4) + (idx & 15)] + ern;
        e = (e > 0.f) ? e : 0.2f * e;
        lw2[idx] = (j < dg) ? __expf(e) : 0.f;
    }
    __syncthreads();

    int b = t >> 4, c4 = t & 15;
    int t4 = t << 2;
    float4 acc = {0.f, 0.f, 0.f, 0.f};
    float den = 0.f;
    for (int g = 0; g < MAXD / 8; g++) {
        if (g * 8 >= dg) break;              // block-uniform
        #pragma unroll
        for (int u = 0; u < 8; u++) {
            int j = g * 8 + u;
            int s = nb[j];                   // scalar load
            float w = lw2[(j << 4) + b];     // broadcast ds_read
            den += w;
            float4 f = *(const float4*)&feat2[(s << 10) + t4];
            acc.x += w * f.x; acc.y += w * f.y; acc.z += w * f.z; acc.w += w * f.w;
        }
    }
    float inv = 1.f / den;
    float4 bb = *(const float4*)&b2v[c4 * 4];
    float4 o = { acc.x * inv + bb.x, acc.y * inv + bb.y,
                 acc.z * inv + bb.z, acc.w * inv + bb.w };
    *(float4*)&out2[(n << 10) + t4] = o;
}

// ---------------- transpose out2[n][b][c] -> out[b][c][n] ----------------
__global__ __launch_bounds__(256) void k_trans(const float* __restrict__ out2,
                                               float* __restrict__ out) {
    __shared__ float tile[64][65];
    int t = threadIdx.x;
    int b = blockIdx.y;
    int n0 = blockIdx.x * 64;
    int i = t >> 2;
    int c0 = (t & 3) * 4;
    #pragma unroll
    for (int p = 0; p < 4; p++) {
        int c = c0 + p * 16;
        float4 v = *(const float4*)&out2[(size_t)(n0 + i) * (BATCH * OUT_CH) + b * OUT_CH + c];
        tile[i][c] = v.x; tile[i][c + 1] = v.y; tile[i][c + 2] = v.z; tile[i][c + 3] = v.w;
    }
    __syncthreads();
    int nl = t & 63;
    int cw = t >> 6;
    #pragma unroll
    for (int q = 0; q < 16; q++) {
        int c = q * 4 + cw;
        out[(size_t)(b * OUT_CH + c) * N_NODES + n0 + nl] = tile[nl][c];
    }
}

extern "C" void kernel_launch(void* const* d_in, const int* in_sizes, int n_in,
                              void* d_out, int out_size, void* d_ws, size_t ws_size,
                              hipStream_t stream) {
    const float* x   = (const float*)d_in[0];
    const float* W1  = (const float*)d_in[1];
    const float* al1 = (const float*)d_in[2];
    const float* ar1 = (const float*)d_in[3];
    const float* b1v = (const float*)d_in[4];
    const float* W2  = (const float*)d_in[5];
    const float* al2 = (const float*)d_in[6];
    const float* ar2 = (const float*)d_in[7];
    const float* b2v = (const float*)d_in[8];
    const int* srcA  = (const int*)d_in[9];
    const int* dstA  = (const int*)d_in[10];
    int E = in_sizes[9];

    char* ws = (char*)d_ws;
    int*   cursor = (int*)(ws);                    // 16 KB; after k_fill == degree
    int*   nbrp   = (int*)(ws + 16384);            // 1 MB
    float* feat1  = (float*)(ws + 1064960);        // 8.39 MB  [n][b][32]
    float* el1    = (float*)(ws + 9453568);        // 1.05 MB  [n][b][4]
    float* er1    = (float*)(ws + 10502144);       // 1.05 MB
    float* feat2  = (float*)(ws + 19939328);       // 16.78 MB [n][b][64]
    float* el2    = (float*)(ws + 36716544);       // 0.26 MB  [n][b]
    float* er2    = (float*)(ws + 36978688);       // 0.26 MB
    float* out2   = feat1;  // 16.78 MB alias over feat1/el1/er1 (+h1 slot; dead by k_gat2)

    float* out = (float*)d_out;
    dim3 blk(256);

    k_init<<<dim3((N_NODES * MAXD + 255) / 256), blk, 0, stream>>>(cursor, nbrp);
    k_fill<<<dim3((E + 255) / 256), blk, 0, stream>>>(srcA, dstA, E, cursor, nbrp);

    k_feat1<<<dim3(N_NODES / 64, BATCH), blk, 0, stream>>>(x, W1, al1, ar1, feat1, el1, er1);
    k_gat1f<<<dim3(N_NODES), blk, 0, stream>>>(feat1, el1, er1, nbrp, cursor, b1v,
                                               W2, al2, ar2, feat2, el2, er2);

    k_gat2 <<<dim3(N_NODES), blk, 0, stream>>>(feat2, el2, er2, nbrp, cursor, b2v, out2);

    k_trans<<<dim3(N_NODES / 64, BATCH), blk, 0, stream>>>(out2, out);
}

// Round 9
// 210.970 us; speedup vs baseline: 2.4506x; 1.0019x over previous
//
#include <hip/hip_runtime.h>
#include <hip/hip_bf16.h>

#define N_NODES 4096
#define BATCH 16
#define IN_CH 128
#define HID 8
#define HEADS 4
#define F1 (HEADS*HID)   // 32
#define OUT_CH 64
#define MAXD 64          // padded degree; true max ~51 (two drifting 5x5 windows + self)

// XCD-bijective swizzle for grid==4096: 8 XCDs x 512 contiguous nodes
__device__ __forceinline__ int node_swz(int bid) {
    return (bid & 7) * 512 + (bid >> 3);
}

// ---------------- graph build ----------------
// cursor-only zero (nbrp is NOT prefilled; consumers select s = j<dg ? nb[j] : n)
__global__ void k_init(int* cursor) {
    int i = blockIdx.x * 256 + threadIdx.x;
    if (i < N_NODES) cursor[i] = 0;
}

__global__ void k_fill(const int* __restrict__ srcA, const int* __restrict__ dstA, int E,
                       int* cursor, int* nbrp) {
    int e = blockIdx.x * 256 + threadIdx.x;
    if (e < E) {
        int n = dstA[e];
        int pos = atomicAdd(&cursor[n], 1);
        nbrp[(n << 6) + pos] = srcA[e];
    }
}

// ---------------- Layer 1 projection -> feat1[n][b][32], el1/er1[n][b][4] ----------------
// 64 nodes x 1 batch per block; thread t = q*64 + nl; head q owns outputs q*8..q*8+8.
__global__ __launch_bounds__(256) void k_feat1(const float* __restrict__ x,
                                               const float* __restrict__ W1,
                                               const float* __restrict__ al1,
                                               const float* __restrict__ ar1,
                                               float* __restrict__ feat1,
                                               float* __restrict__ el1,
                                               float* __restrict__ er1) {
    __shared__ float lW1[IN_CH * F1];    // 16 KB
    __shared__ float lal[F1], lar[F1];
    __shared__ float lt[64 * 33];        // 8.25 KB transpose tile
    __shared__ float lel[64 * 4], ler[64 * 4];   // 2 KB
    int t = threadIdx.x;
    for (int i = t; i < IN_CH * F1; i += 256) lW1[i] = W1[i];
    if (t < F1) { lal[t] = al1[t]; lar[t] = ar1[t]; }
    __syncthreads();

    int b = blockIdx.y;
    int n0 = blockIdx.x * 64;
    int q = t >> 6;          // channel group == head == wave id
    int nl = t & 63;
    int n = n0 + nl;
    const float* xp = x + (size_t)b * (IN_CH * N_NODES) + n;
    const float* wq = lW1 + q * HID;

    float acc[HID];
    #pragma unroll
    for (int i = 0; i < HID; i++) acc[i] = 0.f;
    #pragma unroll 4
    for (int c = 0; c < IN_CH; c++) {
        float xv = xp[(size_t)c * N_NODES];          // 64-lane coalesced
        #pragma unroll
        for (int i = 0; i < HID; i++) acc[i] += xv * wq[c * F1 + i];   // LDS broadcast
    }

    float el = 0.f, er = 0.f;
    #pragma unroll
    for (int i = 0; i < HID; i++) {
        el += acc[i] * lal[q * HID + i];
        er += acc[i] * lar[q * HID + i];
    }
    lel[nl * 4 + q] = el;
    ler[nl * 4 + q] = er;

    #pragma unroll
    for (int i = 0; i < HID; i++) lt[nl * 33 + q * HID + i] = acc[i];
    __syncthreads();

    float* fp = feat1 + (size_t)n0 * (BATCH * F1) + b * F1;
    #pragma unroll
    for (int k = 0; k < 8; k++) {
        int idx = k * 256 + t;          // 64 nodes * 32 feats
        int nn = idx >> 5, f = idx & 31;
        fp[nn * (BATCH * F1) + f] = lt[nn * 33 + f];
    }
    if (t < 64) {
        ((float4*)el1)[(n0 + t) * BATCH + b] = *(float4*)&lel[t * 4];
        ((float4*)er1)[(n0 + t) * BATCH + b] = *(float4*)&ler[t * 4];
    }
}

// ---------------- Fused layer-1 gather + mish + layer-2 projection ----------------
// Block per node. Phase A (degree-gated): per-edge weights w[j][b*4+h] into LDS, once.
// Phase B: gather with conflict-free ds_read broadcast. Phase C: h @ W2 (W2 via L1/L2,
// not LDS -- saves 8KB -> 8 blocks/CU). h1 never touches global memory.
__global__ __launch_bounds__(256) void k_gat1f(const float* __restrict__ feat1,
                                               const float* __restrict__ el1,
                                               const float* __restrict__ er1,
                                               const int* __restrict__ nbrp,
                                               const int* __restrict__ deg,
                                               const float* __restrict__ b1v,
                                               const float* __restrict__ W2,
                                               const float* __restrict__ al2,
                                               const float* __restrict__ ar2,
                                               float* __restrict__ feat2,
                                               float* __restrict__ el2,
                                               float* __restrict__ er2) {
    __shared__ float lw[MAXD * 64];      // 16 KB: w[j][b*4+h]
    __shared__ float lae[2 * OUT_CH];    // 512 B
    __shared__ float lh[BATCH * F1];     // 2 KB
    __shared__ float lb1[F1];
    int t = threadIdx.x;
    int n = node_swz(blockIdx.x);
    if (t < 2 * OUT_CH) lae[t] = (t < OUT_CH) ? al2[t] : ar2[t - OUT_CH];
    if (t < F1) lb1[t] = b1v[t];

    int dg = deg[n];
    int dgc8 = (dg + 7) & ~7;            // phase B reads lw up to ceil8(dg); fill zeros there
    const int* nb = nbrp + (n << 6);

    // phase A: weights for j < dgc8, 4 j per iteration (j = 4r + t>>6, wave-uniform)
    float ern = er1[(n << 6) + (t & 63)];
    for (int r = 0; r * 4 < dgc8; r++) {
        int idx = r * 256 + t;
        int j = idx >> 6;                          // wave-uniform
        int s = (j < dg) ? nb[j] : n;              // scalar select (nbrp not prefilled)
        float e = el1[(s << 6) + (idx & 63)] + ern;   // coalesced 256B per wave
        e = (e > 0.f) ? e : 0.2f * e;
        lw[idx] = (j < dg) ? __expf(e) : 0.f;
    }
    __syncthreads();

    // phase B: gather; thread = (b = t>>4, c2 = t&15 float2 slot), h = c2>>2
    int b = t >> 4, c2 = t & 15;
    int woff = (b << 2) + (c2 >> 2);
    int t2 = t << 1;
    float ax = 0.f, ay = 0.f, wsum = 0.f;
    for (int g = 0; g < MAXD / 8; g++) {
        if (g * 8 >= dg) break;                // block-uniform
        #pragma unroll
        for (int u = 0; u < 8; u++) {
            int j = g * 8 + u;
            int s = (j < dg) ? nb[j] : n;      // scalar select
            float w = lw[(j << 6) + woff];     // conflict-free broadcast
            wsum += w;
            float2 f = *(const float2*)&feat1[(s << 9) + t2];
            ax += w * f.x; ay += w * f.y;
        }
    }
    float inv = 1.f / wsum;
    float v0 = ax * inv + lb1[c2 * 2];
    float v1 = ay * inv + lb1[c2 * 2 + 1];
    // mish(v) = v * p/(p+2), p = t(t+2), t = e^v
    float e0 = __expf(v0), e1 = __expf(v1);
    float p0 = e0 * (e0 + 2.f), p1 = e1 * (e1 + 2.f);
    lh[b * F1 + c2 * 2]     = v0 * p0 / (p0 + 2.f);
    lh[b * F1 + c2 * 2 + 1] = v1 * p1 / (p1 + 2.f);
    __syncthreads();

    // phase C: project 32 -> 64; thread = (b, c4 = t&15); W2 from global (L1 broadcast)
    int c4 = t & 15;
    float hreg[F1];
    #pragma unroll
    for (int k = 0; k < F1; k++) hreg[k] = lh[b * F1 + k];
    float4 acc = {0.f, 0.f, 0.f, 0.f};
    #pragma unroll
    for (int k = 0; k < F1; k++) {
        float4 w4 = *(const float4*)&W2[k * OUT_CH + c4 * 4];
        acc.x += hreg[k] * w4.x; acc.y += hreg[k] * w4.y;
        acc.z += hreg[k] * w4.z; acc.w += hreg[k] * w4.w;
    }
    *(float4*)&feat2[(n << 10) + (t << 2)] = acc;

    float4 a4 = *(float4*)&lae[c4 * 4];
    float4 r4 = *(float4*)&lae[OUT_CH + c4 * 4];
    float pl = acc.x * a4.x + acc.y * a4.y + acc.z * a4.z + acc.w * a4.w;
    float pr = acc.x * r4.x + acc.y * r4.y + acc.z * r4.z + acc.w * r4.w;
    #pragma unroll
    for (int off = 1; off < 16; off <<= 1) {
        pl += __shfl_xor(pl, off, 64);
        pr += __shfl_xor(pr, off, 64);
    }
    if (c4 == 0) { el2[(n << 4) + b] = pl; er2[(n << 4) + b] = pr; }
}

// ---------------- Layer 2 gather: degree-gated LDS weight table + broadcast ----------------
__global__ __launch_bounds__(256) void k_gat2(const float* __restrict__ feat2,
                                              const float* __restrict__ el2,
                                              const float* __restrict__ er2,
                                              const int* __restrict__ nbrp,
                                              const int* __restrict__ deg,
                                              const float* __restrict__ b2v,
                                              float* __restrict__ out2) {
    __shared__ float lw2[MAXD * BATCH];  // 4 KB: w[j][b]
    int t = threadIdx.x;
    int n = node_swz(blockIdx.x);
    int dg = deg[n];
    int dgc8 = (dg + 7) & ~7;
    const int* nb = nbrp + (n << 6);

    // phase A: weights for j < dgc8, 16 j per iteration (j = 16r + t>>4)
    float ern = er2[(n << 4) + (t & 15)];
    for (int r = 0; r * 16 < dgc8; r++) {
        int idx = r * 256 + t;
        int j = idx >> 4;
        int s = (j < dg) ? nb[j] : n;        // per-lane select (j varies within wave)
        float e = el2[(s << 4) + (idx & 15)] + ern;
        e = (e > 0.f) ? e : 0.2f * e;
        lw2[idx] = (j < dg) ? __expf(e) : 0.f;
    }
    __syncthreads();

    int b = t >> 4, c4 = t & 15;
    int t4 = t << 2;
    float4 acc = {0.f, 0.f, 0.f, 0.f};
    float den = 0.f;
    for (int g = 0; g < MAXD / 8; g++) {
        if (g * 8 >= dg) break;              // block-uniform
        #pragma unroll
        for (int u = 0; u < 8; u++) {
            int j = g * 8 + u;
            int s = (j < dg) ? nb[j] : n;    // scalar select
            float w = lw2[(j << 4) + b];     // broadcast ds_read
            den += w;
            float4 f = *(const float4*)&feat2[(s << 10) + t4];
            acc.x += w * f.x; acc.y += w * f.y; acc.z += w * f.z; acc.w += w * f.w;
        }
    }
    float inv = 1.f / den;
    float4 bb = *(const float4*)&b2v[c4 * 4];
    float4 o = { acc.x * inv + bb.x, acc.y * inv + bb.y,
                 acc.z * inv + bb.z, acc.w * inv + bb.w };
    *(float4*)&out2[(n << 10) + t4] = o;
}

// ---------------- transpose out2[n][b][c] -> out[b][c][n] ----------------
__global__ __launch_bounds__(256) void k_trans(const float* __restrict__ out2,
                                               float* __restrict__ out) {
    __shared__ float tile[64][65];
    int t = threadIdx.x;
    int b = blockIdx.y;
    int n0 = blockIdx.x * 64;
    int i = t >> 2;
    int c0 = (t & 3) * 4;
    #pragma unroll
    for (int p = 0; p < 4; p++) {
        int c = c0 + p * 16;
        float4 v = *(const float4*)&out2[(size_t)(n0 + i) * (BATCH * OUT_CH) + b * OUT_CH + c];
        tile[i][c] = v.x; tile[i][c + 1] = v.y; tile[i][c + 2] = v.z; tile[i][c + 3] = v.w;
    }
    __syncthreads();
    int nl = t & 63;
    int cw = t >> 6;
    #pragma unroll
    for (int q = 0; q < 16; q++) {
        int c = q * 4 + cw;
        out[(size_t)(b * OUT_CH + c) * N_NODES + n0 + nl] = tile[nl][c];
    }
}

extern "C" void kernel_launch(void* const* d_in, const int* in_sizes, int n_in,
                              void* d_out, int out_size, void* d_ws, size_t ws_size,
                              hipStream_t stream) {
    const float* x   = (const float*)d_in[0];
    const float* W1  = (const float*)d_in[1];
    const float* al1 = (const float*)d_in[2];
    const float* ar1 = (const float*)d_in[3];
    const float* b1v = (const float*)d_in[4];
    const float* W2  = (const float*)d_in[5];
    const float* al2 = (const float*)d_in[6];
    const float* ar2 = (const float*)d_in[7];
    const float* b2v = (const float*)d_in[8];
    const int* srcA  = (const int*)d_in[9];
    const int* dstA  = (const int*)d_in[10];
    int E = in_sizes[9];

    char* ws = (char*)d_ws;
    int*   cursor = (int*)(ws);                    // 16 KB; after k_fill == degree
    int*   nbrp   = (int*)(ws + 16384);            // 1 MB (slots >= deg are garbage; selected out)
    float* feat1  = (float*)(ws + 1064960);        // 8.39 MB  [n][b][32]
    float* el1    = (float*)(ws + 9453568);        // 1.05 MB  [n][b][4]
    float* er1    = (float*)(ws + 10502144);       // 1.05 MB
    float* feat2  = (float*)(ws + 19939328);       // 16.78 MB [n][b][64]
    float* el2    = (float*)(ws + 36716544);       // 0.26 MB  [n][b]
    float* er2    = (float*)(ws + 36978688);       // 0.26 MB
    float* out2   = feat1;  // 16.78 MB alias over feat1/el1/er1 (dead by k_gat2)

    float* out = (float*)d_out;
    dim3 blk(256);

    k_init<<<dim3(16), blk, 0, stream>>>(cursor);
    k_fill<<<dim3((E + 255) / 256), blk, 0, stream>>>(srcA, dstA, E, cursor, nbrp);

    k_feat1<<<dim3(N_NODES / 64, BATCH), blk, 0, stream>>>(x, W1, al1, ar1, feat1, el1, er1);
    k_gat1f<<<dim3(N_NODES), blk, 0, stream>>>(feat1, el1, er1, nbrp, cursor, b1v,
                                               W2, al2, ar2, feat2, el2, er2);

    k_gat2 <<<dim3(N_NODES), blk, 0, stream>>>(feat2, el2, er2, nbrp, cursor, b2v, out2);

    k_trans<<<dim3(N_NODES / 64, BATCH), blk, 0, stream>>>(out2, out);
}